// Round 1
// 717.628 us; speedup vs baseline: 1.0749x; 1.0749x over previous
//
#include <hip/hip_runtime.h>
#include <math.h>

#define PI2 6.283185307179586f

typedef float floatx4 __attribute__((ext_vector_type(4)));

// Problem constants: B=32, H=W=64, C1=32, C2=64, K=5, FC1=512, HW=4096, FLAT=262144
// Algebra: y = fc2( fc1( flat(h2) ) ), h2[b,o,hw] = |x[b,hw]| * t[o,hw],
//          t[o,hw] = |sum_i a1[i,hw] * kf2[o,i,hw]|, a1[i,hw] = |kf1[i,hw]|.
// So y1[b,f] = sum_hw |x[b,hw]| * W1eff[f,hw],  W1eff[f,hw] = sum_o t[o,hw]*fc1_w[f,o*4096+hw].
// Only mandatory HBM traffic: fc1_w, 512 MB, read exactly once (k3).

// ---------- kA: fused (k1) a1[i,hw]=|fft2(pad(w1))| and (k2a) row-DFT of w2 ----------
__global__ void kA_small(const float* __restrict__ w1r, const float* __restrict__ w1i,
                         const float* __restrict__ w2r, const float* __restrict__ w2i,
                         float* __restrict__ a1, float* __restrict__ G_re,
                         float* __restrict__ G_im) {
    if (blockIdx.x < 512) {
        // k1: a1 (32 x 4096)
        int idx = blockIdx.x * 256 + threadIdx.x;   // i*4096 + hw
        int i  = idx >> 12;
        int hw = idx & 4095;
        int u = hw >> 6, v = hw & 63;
        const float* wr = w1r + i * 25;
        const float* wi = w1i + i * 25;
        float re = 0.f, im = 0.f;
        #pragma unroll
        for (int p = 0; p < 5; ++p) {
            #pragma unroll
            for (int q = 0; q < 5; ++q) {
                float s, c;
                sincosf(-(PI2 / 64.f) * (float)((u * p + v * q) & 63), &s, &c);
                float ar = wr[p * 5 + q], ai = wi[p * 5 + q];
                re += ar * c - ai * s;
                im += ar * s + ai * c;
            }
        }
        a1[idx] = sqrtf(re * re + im * im);
    } else {
        // k2a: G[o,i,p,v] = sum_q w2[o,i,p,q] * e^{-2pi i (v q)/64}, de-interleaved planes
        int idx = (blockIdx.x - 512) * 256 + threadIdx.x;  // ((oi*5)+p)*64 + v
        int v  = idx & 63;
        int p  = (idx >> 6) % 5;
        int oi = idx / 320;
        const float* wr = w2r + oi * 25 + p * 5;
        const float* wi = w2i + oi * 25 + p * 5;
        float re = 0.f, im = 0.f;
        #pragma unroll
        for (int q = 0; q < 5; ++q) {
            float s, c;
            sincosf(-(PI2 / 64.f) * (float)((v * q) & 63), &s, &c);
            re += wr[q] * c - wi[q] * s;
            im += wr[q] * s + wi[q] * c;
        }
        G_re[idx] = re;
        G_im[idx] = im;
    }
}

// ---------- k2b: t[o,hw] = | sum_i a1[i,hw] * (sum_p e_u[p] * G[o,i,p,v]) | ----------
// 512 blocks (o x 8 u-rows) -> 2 blocks/CU, 8 waves/CU (was 4: latency-bound).
// G[o] slice staged in LDS, de-interleaved planes so inner reads are stride-1
// (v contiguous -> 2 lanes/bank, conflict-free). Twiddles from a 64-entry LDS LUT:
// a wave's 64 lanes share one u -> broadcast reads, no sincos in the hot loop.
__global__ __launch_bounds__(256) void k2b_t(
        const float* __restrict__ G_re, const float* __restrict__ G_im,
        const float* __restrict__ a1, float* __restrict__ t) {
    __shared__ float Gsr[5120];   // 16 i's: 16*5*64 floats (re)
    __shared__ float Gsi[5120];   // (im)
    __shared__ float twc[64];
    __shared__ float tws[64];
    int o  = blockIdx.x >> 3;
    int ug = blockIdx.x & 7;
    if (threadIdx.x < 64) {
        float s, c;
        sincosf(-(PI2 / 64.f) * (float)threadIdx.x, &s, &c);
        twc[threadIdx.x] = c;
        tws[threadIdx.x] = s;
    }
    float re[2] = {0.f, 0.f};
    float im[2] = {0.f, 0.f};
    for (int half = 0; half < 2; ++half) {
        __syncthreads();
        for (int jj = threadIdx.x; jj < 5120; jj += 256) {
            Gsr[jj] = G_re[o * 10240 + half * 5120 + jj];
            Gsi[jj] = G_im[o * 10240 + half * 5120 + jj];
        }
        __syncthreads();
        #pragma unroll
        for (int jt = 0; jt < 2; ++jt) {
            int j = jt * 256 + threadIdx.x;     // 0..511 within this block's uv range
            int u = ug * 8 + (j >> 6);
            int v = j & 63;
            float cu[5], su[5];
            #pragma unroll
            for (int p = 0; p < 5; ++p) {
                int k = (u * p) & 63;
                cu[p] = twc[k];
                su[p] = tws[k];
            }
            #pragma unroll 4
            for (int i = 0; i < 16; ++i) {
                float a = a1[(half * 16 + i) * 4096 + u * 64 + v];
                float sr = 0.f, si = 0.f;
                #pragma unroll
                for (int p = 0; p < 5; ++p) {
                    float gr = Gsr[(i * 5 + p) * 64 + v];
                    float gi = Gsi[(i * 5 + p) * 64 + v];
                    sr += gr * cu[p] - gi * su[p];
                    si += gr * su[p] + gi * cu[p];
                }
                re[jt] += a * sr;
                im[jt] += a * si;
            }
        }
    }
    #pragma unroll
    for (int jt = 0; jt < 2; ++jt) {
        int j = jt * 256 + threadIdx.x;
        int u = ug * 8 + (j >> 6);
        int v = j & 63;
        t[o * 4096 + u * 64 + v] = sqrtf(re[jt] * re[jt] + im[jt] * im[jt]);
    }
}

// ---------- k3: THE memory-bound pass. Streams fc1_w (512 MB) exactly once. ----------
// 2 FC1 rows per block; W1eff fragments live in registers; nontemporal on the
// 512 MB stream so L2 keeps t (1 MB) and x (0.5 MB) resident.
__global__ __launch_bounds__(256) void k3_y1(
        const float* __restrict__ fc1_w, const float* __restrict__ t,
        const float* __restrict__ x, float* __restrict__ y1) {
    int f0 = (blockIdx.x >> 2) * 2;
    int hb = blockIdx.x & 3;
    int hw = hb * 1024 + threadIdx.x * 4;
    const floatx4* w0 = (const floatx4*)(fc1_w + (size_t)f0 * 262144);
    const floatx4* w1 = (const floatx4*)(fc1_w + (size_t)(f0 + 1) * 262144);
    floatx4 acc0 = (floatx4)(0.f);
    floatx4 acc1 = (floatx4)(0.f);
    #pragma unroll 16
    for (int o = 0; o < 64; ++o) {
        int e = (o * 4096 + hw) >> 2;
        floatx4 tv = *(const floatx4*)(t + o * 4096 + hw);
        floatx4 wa = __builtin_nontemporal_load(w0 + e);
        floatx4 wb = __builtin_nontemporal_load(w1 + e);
        acc0 += tv * wa;
        acc1 += tv * wb;
    }
    __shared__ float red[4][32][2];
    int wave = threadIdx.x >> 6;
    int lane = threadIdx.x & 63;
    for (int b = 0; b < 32; ++b) {
        floatx4 xv = *(const floatx4*)(x + b * 4096 + hw);
        float ax = fabsf(xv.x), ay = fabsf(xv.y), az = fabsf(xv.z), aw = fabsf(xv.w);
        float p0 = acc0.x * ax + acc0.y * ay + acc0.z * az + acc0.w * aw;
        float p1 = acc1.x * ax + acc1.y * ay + acc1.z * az + acc1.w * aw;
        #pragma unroll
        for (int m = 32; m >= 1; m >>= 1) {
            p0 += __shfl_xor(p0, m, 64);
            p1 += __shfl_xor(p1, m, 64);
        }
        if (lane == 0) { red[wave][b][0] = p0; red[wave][b][1] = p1; }
    }
    __syncthreads();
    if (threadIdx.x < 64) {
        int b = threadIdx.x >> 1, ff = threadIdx.x & 1;
        float s = red[0][b][ff] + red[1][b][ff] + red[2][b][ff] + red[3][b][ff];
        atomicAdd(&y1[b * 512 + f0 + ff], s);
    }
}

// ---------- k4: out[b,c] = sum_f fc2_w[c,f]*(y1[b,f]+fc1_b[f]) + fc2_b[c] ----------
// One block per batch row (was a single 320-thread block: serial latency-bound).
// Coalesced fc2_w reads; butterfly reduce across the wave.
__global__ __launch_bounds__(64) void k4_out(
        const float* __restrict__ y1, const float* __restrict__ fc1_b,
        const float* __restrict__ fc2_w, const float* __restrict__ fc2_b,
        float* __restrict__ out) {
    int b = blockIdx.x;
    int lane = threadIdx.x;     // 64 lanes, one wave
    float acc[10];
    #pragma unroll
    for (int c = 0; c < 10; ++c) acc[c] = 0.f;
    #pragma unroll
    for (int k = 0; k < 8; ++k) {
        int f = k * 64 + lane;
        float v = y1[b * 512 + f] + fc1_b[f];
        #pragma unroll
        for (int c = 0; c < 10; ++c)
            acc[c] += fc2_w[c * 512 + f] * v;
    }
    #pragma unroll
    for (int c = 0; c < 10; ++c) {
        #pragma unroll
        for (int m = 32; m >= 1; m >>= 1)
            acc[c] += __shfl_xor(acc[c], m, 64);
    }
    if (lane == 0) {
        #pragma unroll
        for (int c = 0; c < 10; ++c)
            out[b * 10 + c] = acc[c] + fc2_b[c];
    }
}

extern "C" void kernel_launch(void* const* d_in, const int* in_sizes, int n_in,
                              void* d_out, int out_size, void* d_ws, size_t ws_size,
                              hipStream_t stream) {
    const float* x    = (const float*)d_in[0];
    const float* w1r  = (const float*)d_in[1];
    const float* w1i  = (const float*)d_in[2];
    const float* w2r  = (const float*)d_in[3];
    const float* w2i  = (const float*)d_in[4];
    const float* fc1w = (const float*)d_in[5];
    const float* fc1b = (const float*)d_in[6];
    const float* fc2w = (const float*)d_in[7];
    const float* fc2b = (const float*)d_in[8];
    float* out = (float*)d_out;

    // workspace (floats): a1[131072] | G_re[655360] | G_im[655360] | t[262144] | y1[16384]
    float* a1   = (float*)d_ws;
    float* G_re = a1 + 131072;
    float* G_im = G_re + 655360;
    float* t    = G_im + 655360;
    float* y1   = t + 262144;

    (void)hipMemsetAsync(y1, 0, 16384 * sizeof(float), stream);   // ws is poisoned 0xAA
    kA_small<<<3072, 256, 0, stream>>>(w1r, w1i, w2r, w2i, a1, G_re, G_im);
    k2b_t<<<512, 256, 0, stream>>>(G_re, G_im, a1, t);
    k3_y1<<<1024, 256, 0, stream>>>(fc1w, t, x, y1);        // 256 f-pairs x 4 hw-blocks
    k4_out<<<32, 64, 0, stream>>>(y1, fc1b, fc2w, fc2b, out);
}

// Round 2
// 700.960 us; speedup vs baseline: 1.1004x; 1.0238x over previous
//
#include <hip/hip_runtime.h>
#include <math.h>

#define PI2 6.283185307179586f

typedef float floatx4 __attribute__((ext_vector_type(4)));

// Problem constants: B=32, H=W=64, C1=32, C2=64, K=5, FC1=512, HW=4096, FLAT=262144
// Algebra: y = fc2( fc1( flat(h2) ) ), h2[b,o,hw] = |x[b,hw]| * t[o,hw],
//          t[o,hw] = |sum_i a1[i,hw] * kf2[o,i,hw]|, a1[i,hw] = |kf1[i,hw]|.
// So y1[b,f] = sum_hw |x[b,hw]| * W1eff[f,hw],  W1eff[f,hw] = sum_o t[o,hw]*fc1_w[f,o*4096+hw].
// Only mandatory HBM traffic: fc1_w, 512 MB, read exactly once (k3, 85 us floor).

// ---------- kA: fused (k1) a1[i,hw]=|fft2(pad(w1))| and (k2a) row-DFT of w2 ----------
// Twiddles from a 64-entry LDS LUT instead of 25/5 libm sincosf calls per thread.
__global__ __launch_bounds__(256) void kA_small(
        const float* __restrict__ w1r, const float* __restrict__ w1i,
        const float* __restrict__ w2r, const float* __restrict__ w2i,
        float* __restrict__ a1, float* __restrict__ G_re,
        float* __restrict__ G_im) {
    __shared__ float twc[64];
    __shared__ float tws[64];
    if (threadIdx.x < 64) {
        float s, c;
        sincosf(-(PI2 / 64.f) * (float)threadIdx.x, &s, &c);
        twc[threadIdx.x] = c;
        tws[threadIdx.x] = s;
    }
    __syncthreads();
    if (blockIdx.x < 512) {
        // k1: a1 (32 x 4096)
        int idx = blockIdx.x * 256 + threadIdx.x;   // i*4096 + hw
        int i  = idx >> 12;
        int hw = idx & 4095;
        int u = hw >> 6, v = hw & 63;
        const float* wr = w1r + i * 25;
        const float* wi = w1i + i * 25;
        float re = 0.f, im = 0.f;
        #pragma unroll
        for (int p = 0; p < 5; ++p) {
            #pragma unroll
            for (int q = 0; q < 5; ++q) {
                int k = (u * p + v * q) & 63;
                float c = twc[k], s = tws[k];
                float ar = wr[p * 5 + q], ai = wi[p * 5 + q];
                re += ar * c - ai * s;
                im += ar * s + ai * c;
            }
        }
        a1[idx] = sqrtf(re * re + im * im);
    } else {
        // k2a: G[o,i,p,v] = sum_q w2[o,i,p,q] * e^{-2pi i (v q)/64}, de-interleaved planes
        int idx = (blockIdx.x - 512) * 256 + threadIdx.x;  // ((oi*5)+p)*64 + v
        int v  = idx & 63;
        int p  = (idx >> 6) % 5;
        int oi = idx / 320;
        const float* wr = w2r + oi * 25 + p * 5;
        const float* wi = w2i + oi * 25 + p * 5;
        float re = 0.f, im = 0.f;
        #pragma unroll
        for (int q = 0; q < 5; ++q) {
            int k = (v * q) & 63;
            float c = twc[k], s = tws[k];
            re += wr[q] * c - wi[q] * s;
            im += wr[q] * s + wi[q] * c;
        }
        G_re[idx] = re;
        G_im[idx] = im;
    }
}

// ---------- k2b: t[o,hw] = | sum_i a1[i,hw] * (sum_p e_u[p] * G[o,i,p,v]) | ----------
// 512 blocks (o x 8 u-rows) -> 2 blocks/CU, 8 waves/CU. G[o] slice staged in LDS,
// de-interleaved planes so inner reads are stride-1 (v contiguous -> 2 lanes/bank,
// conflict-free). Twiddles from a 64-entry LDS LUT: a wave's 64 lanes share one u
// -> broadcast reads, no sincos in the hot loop.
__global__ __launch_bounds__(256) void k2b_t(
        const float* __restrict__ G_re, const float* __restrict__ G_im,
        const float* __restrict__ a1, float* __restrict__ t) {
    __shared__ float Gsr[5120];   // 16 i's: 16*5*64 floats (re)
    __shared__ float Gsi[5120];   // (im)
    __shared__ float twc[64];
    __shared__ float tws[64];
    int o  = blockIdx.x >> 3;
    int ug = blockIdx.x & 7;
    if (threadIdx.x < 64) {
        float s, c;
        sincosf(-(PI2 / 64.f) * (float)threadIdx.x, &s, &c);
        twc[threadIdx.x] = c;
        tws[threadIdx.x] = s;
    }
    float re[2] = {0.f, 0.f};
    float im[2] = {0.f, 0.f};
    for (int half = 0; half < 2; ++half) {
        __syncthreads();
        for (int jj = threadIdx.x; jj < 5120; jj += 256) {
            Gsr[jj] = G_re[o * 10240 + half * 5120 + jj];
            Gsi[jj] = G_im[o * 10240 + half * 5120 + jj];
        }
        __syncthreads();
        #pragma unroll
        for (int jt = 0; jt < 2; ++jt) {
            int j = jt * 256 + threadIdx.x;     // 0..511 within this block's uv range
            int u = ug * 8 + (j >> 6);
            int v = j & 63;
            float cu[5], su[5];
            #pragma unroll
            for (int p = 0; p < 5; ++p) {
                int k = (u * p) & 63;
                cu[p] = twc[k];
                su[p] = tws[k];
            }
            #pragma unroll 4
            for (int i = 0; i < 16; ++i) {
                float a = a1[(half * 16 + i) * 4096 + u * 64 + v];
                float sr = 0.f, si = 0.f;
                #pragma unroll
                for (int p = 0; p < 5; ++p) {
                    float gr = Gsr[(i * 5 + p) * 64 + v];
                    float gi = Gsi[(i * 5 + p) * 64 + v];
                    sr += gr * cu[p] - gi * su[p];
                    si += gr * su[p] + gi * cu[p];
                }
                re[jt] += a * sr;
                im[jt] += a * si;
            }
        }
    }
    #pragma unroll
    for (int jt = 0; jt < 2; ++jt) {
        int j = jt * 256 + threadIdx.x;
        int u = ug * 8 + (j >> 6);
        int v = j & 63;
        t[o * 4096 + u * 64 + v] = sqrtf(re[jt] * re[jt] + im[jt] * im[jt]);
    }
}

// ---------- k3: THE memory-bound pass. Streams fc1_w (512 MB) exactly once. ----------
// 2 FC1 rows per block; W1eff fragments live in registers; nontemporal (evict-first)
// on the 512 MB stream so L2 keeps t (1 MB) and x (0.5 MB) resident.
// Per-hb partial outputs instead of atomics -> no y1 memset dispatch needed.
__global__ __launch_bounds__(256) void k3_y1(
        const float* __restrict__ fc1_w, const float* __restrict__ t,
        const float* __restrict__ x, float* __restrict__ y1p) {
    int f0 = (blockIdx.x >> 2) * 2;
    int hb = blockIdx.x & 3;
    int hw = hb * 1024 + threadIdx.x * 4;
    const floatx4* w0 = (const floatx4*)(fc1_w + (size_t)f0 * 262144);
    const floatx4* w1 = (const floatx4*)(fc1_w + (size_t)(f0 + 1) * 262144);
    floatx4 acc0 = (floatx4)(0.f);
    floatx4 acc1 = (floatx4)(0.f);
    #pragma unroll 16
    for (int o = 0; o < 64; ++o) {
        int e = (o * 4096 + hw) >> 2;
        floatx4 tv = *(const floatx4*)(t + o * 4096 + hw);
        floatx4 wa = __builtin_nontemporal_load(w0 + e);
        floatx4 wb = __builtin_nontemporal_load(w1 + e);
        acc0 += tv * wa;
        acc1 += tv * wb;
    }
    __shared__ float red[4][32][2];
    int wave = threadIdx.x >> 6;
    int lane = threadIdx.x & 63;
    for (int b = 0; b < 32; ++b) {
        floatx4 xv = *(const floatx4*)(x + b * 4096 + hw);
        float ax = fabsf(xv.x), ay = fabsf(xv.y), az = fabsf(xv.z), aw = fabsf(xv.w);
        float p0 = acc0.x * ax + acc0.y * ay + acc0.z * az + acc0.w * aw;
        float p1 = acc1.x * ax + acc1.y * ay + acc1.z * az + acc1.w * aw;
        #pragma unroll
        for (int m = 32; m >= 1; m >>= 1) {
            p0 += __shfl_xor(p0, m, 64);
            p1 += __shfl_xor(p1, m, 64);
        }
        if (lane == 0) { red[wave][b][0] = p0; red[wave][b][1] = p1; }
    }
    __syncthreads();
    if (threadIdx.x < 64) {
        int b = threadIdx.x >> 1, ff = threadIdx.x & 1;
        float s = red[0][b][ff] + red[1][b][ff] + red[2][b][ff] + red[3][b][ff];
        y1p[hb * 16384 + b * 512 + f0 + ff] = s;   // partial per hw-quarter
    }
}

// ---------- k4: out[b,c] = sum_f fc2_w[c,f]*(sum_hb y1p[hb,b,f]+fc1_b[f]) + fc2_b[c] ----------
// One block per batch row; coalesced fc2_w reads; butterfly reduce across the wave.
__global__ __launch_bounds__(64) void k4_out(
        const float* __restrict__ y1p, const float* __restrict__ fc1_b,
        const float* __restrict__ fc2_w, const float* __restrict__ fc2_b,
        float* __restrict__ out) {
    int b = blockIdx.x;
    int lane = threadIdx.x;     // 64 lanes, one wave
    float acc[10];
    #pragma unroll
    for (int c = 0; c < 10; ++c) acc[c] = 0.f;
    #pragma unroll
    for (int k = 0; k < 8; ++k) {
        int f = k * 64 + lane;
        float v = y1p[b * 512 + f] + y1p[16384 + b * 512 + f]
                + y1p[32768 + b * 512 + f] + y1p[49152 + b * 512 + f]
                + fc1_b[f];
        #pragma unroll
        for (int c = 0; c < 10; ++c)
            acc[c] += fc2_w[c * 512 + f] * v;
    }
    #pragma unroll
    for (int c = 0; c < 10; ++c) {
        #pragma unroll
        for (int m = 32; m >= 1; m >>= 1)
            acc[c] += __shfl_xor(acc[c], m, 64);
    }
    if (lane == 0) {
        #pragma unroll
        for (int c = 0; c < 10; ++c)
            out[b * 10 + c] = acc[c] + fc2_b[c];
    }
}

extern "C" void kernel_launch(void* const* d_in, const int* in_sizes, int n_in,
                              void* d_out, int out_size, void* d_ws, size_t ws_size,
                              hipStream_t stream) {
    const float* x    = (const float*)d_in[0];
    const float* w1r  = (const float*)d_in[1];
    const float* w1i  = (const float*)d_in[2];
    const float* w2r  = (const float*)d_in[3];
    const float* w2i  = (const float*)d_in[4];
    const float* fc1w = (const float*)d_in[5];
    const float* fc1b = (const float*)d_in[6];
    const float* fc2w = (const float*)d_in[7];
    const float* fc2b = (const float*)d_in[8];
    float* out = (float*)d_out;

    // workspace (floats): a1[131072] | G_re[655360] | G_im[655360] | t[262144] | y1p[65536]
    float* a1   = (float*)d_ws;
    float* G_re = a1 + 131072;
    float* G_im = G_re + 655360;
    float* t    = G_im + 655360;
    float* y1p  = t + 262144;

    kA_small<<<3072, 256, 0, stream>>>(w1r, w1i, w2r, w2i, a1, G_re, G_im);
    k2b_t<<<512, 256, 0, stream>>>(G_re, G_im, a1, t);
    k3_y1<<<1024, 256, 0, stream>>>(fc1w, t, x, y1p);       // 256 f-pairs x 4 hw-blocks
    k4_out<<<32, 64, 0, stream>>>(y1p, fc1b, fc2w, fc2b, out);
}